// Round 1
// baseline (467.937 us; speedup 1.0000x reference)
//
#include <hip/hip_runtime.h>
#include <math.h>

// ---------------- types / helpers ----------------
typedef __attribute__((ext_vector_type(8))) short bf16x8;
typedef __attribute__((ext_vector_type(4))) short bf16x4;
typedef __attribute__((ext_vector_type(4))) float f32x4;

__device__ __forceinline__ unsigned short f2bf(float f) {
  unsigned u = __builtin_bit_cast(unsigned, f);
  u += 0x7fffu + ((u >> 16) & 1u);           // RNE
  return (unsigned short)(u >> 16);
}
__device__ __forceinline__ float bf2f(unsigned short h) {
  return __builtin_bit_cast(float, (unsigned)h << 16);
}

#define MFMA16(a, b, c) __builtin_amdgcn_mfma_f32_16x16x32_bf16((a), (b), (c), 0, 0, 0)

// ---------------- fp32 -> bf16 convert (weights) ----------------
__global__ __launch_bounds__(256) void k_cvt(const float* __restrict__ in,
                                             unsigned short* __restrict__ out) {
  int i = blockIdx.x * 256 + threadIdx.x;
  float4 v = ((const float4*)in)[i];
  bf16x4 o;
  o[0] = (short)f2bf(v.x); o[1] = (short)f2bf(v.y);
  o[2] = (short)f2bf(v.z); o[3] = (short)f2bf(v.w);
  *(bf16x4*)(out + (size_t)i * 4) = o;
}

// ---------------- layernorm (1024 cols, 1 block/row) -> bf16 ----------------
__global__ __launch_bounds__(256) void k_ln(const float* __restrict__ x,
                                            const float* __restrict__ g,
                                            const float* __restrict__ b,
                                            unsigned short* __restrict__ out) {
  __shared__ float red[8];
  const int tid = threadIdx.x;
  const size_t row = blockIdx.x;
  float4 v = ((const float4*)(x + row * 1024))[tid];
  float s = v.x + v.y + v.z + v.w;
#pragma unroll
  for (int off = 32; off; off >>= 1) s += __shfl_xor(s, off);
  if ((tid & 63) == 0) red[tid >> 6] = s;
  __syncthreads();
  float mu = (red[0] + red[1] + red[2] + red[3]) * (1.0f / 1024.0f);
  float dx = v.x - mu, dy = v.y - mu, dz = v.z - mu, dw = v.w - mu;
  float s2 = dx * dx + dy * dy + dz * dz + dw * dw;
#pragma unroll
  for (int off = 32; off; off >>= 1) s2 += __shfl_xor(s2, off);
  if ((tid & 63) == 0) red[4 + (tid >> 6)] = s2;
  __syncthreads();
  float var = (red[4] + red[5] + red[6] + red[7]) * (1.0f / 1024.0f);
  float rstd = rsqrtf(var + 1e-5f);
  float4 gv = ((const float4*)g)[tid];
  float4 bv = ((const float4*)b)[tid];
  bf16x4 o;
  o[0] = (short)f2bf(dx * rstd * gv.x + bv.x);
  o[1] = (short)f2bf(dy * rstd * gv.y + bv.y);
  o[2] = (short)f2bf(dz * rstd * gv.z + bv.z);
  o[3] = (short)f2bf(dw * rstd * gv.w + bv.w);
  *(bf16x4*)(out + row * 1024 + tid * 4) = o;
}

// ---------------- bt-GEMM: C[M,N] = A[M,K] @ B[N,K]^T, bf16 MFMA ----------------
// EPI 0: store bf16
// EPI 1: v += bias[col]; v = gelu_exact(v); store bf16
// EPI 2: v = resid[row,col] + (v + bias[col]) * gamma[col]; store f32
template <int EPI>
__global__ __launch_bounds__(256) void k_gemm_bt(
    const unsigned short* __restrict__ A, const unsigned short* __restrict__ Bw,
    int Ndim, int K,
    const float* __restrict__ bias, const float* __restrict__ gamma,
    const float* __restrict__ resid,
    unsigned short* __restrict__ outb, float* __restrict__ outf) {
  __shared__ __align__(16) unsigned short sA[128 * 64];
  __shared__ __align__(16) unsigned short sB[128 * 64];
  const int tid = threadIdx.x;
  const int wid = tid >> 6, lane = tid & 63;
  const int wr = wid >> 1, wc = wid & 1;
  const int lr = lane & 15, lhi = lane >> 4;
  const int brow = blockIdx.y, bcol = blockIdx.x;

  const size_t a_base = (size_t)brow * 128 * K;
  const size_t b_base = (size_t)bcol * 128 * K;
  const int srow = tid >> 3;       // 0..31
  const int scol = (tid & 7) * 8;  // 0..56

  f32x4 acc[4][4] = {};

  for (int k0 = 0; k0 < K; k0 += 64) {
    __syncthreads();  // protect LDS from previous iteration's readers
#pragma unroll
    for (int r = 0; r < 4; ++r) {
      int row = r * 32 + srow;
      *(bf16x8*)&sA[row * 64 + scol] =
          *(const bf16x8*)&A[a_base + (size_t)row * K + k0 + scol];
      *(bf16x8*)&sB[row * 64 + scol] =
          *(const bf16x8*)&Bw[b_base + (size_t)row * K + k0 + scol];
    }
    __syncthreads();
#pragma unroll
    for (int kk = 0; kk < 2; ++kk) {
      bf16x8 af[4], bfr[4];
#pragma unroll
      for (int i = 0; i < 4; ++i) {
        int ar = wr * 64 + i * 16 + lr;
        af[i] = *(const bf16x8*)&sA[ar * 64 + kk * 32 + lhi * 8];
        int br = wc * 64 + i * 16 + lr;
        bfr[i] = *(const bf16x8*)&sB[br * 64 + kk * 32 + lhi * 8];
      }
#pragma unroll
      for (int i = 0; i < 4; ++i)
#pragma unroll
        for (int j = 0; j < 4; ++j)
          acc[i][j] = MFMA16(af[i], bfr[j], acc[i][j]);
    }
  }

#pragma unroll
  for (int i = 0; i < 4; ++i)
#pragma unroll
    for (int j = 0; j < 4; ++j)
#pragma unroll
      for (int r = 0; r < 4; ++r) {
        int row = brow * 128 + wr * 64 + i * 16 + lhi * 4 + r;
        int col = bcol * 128 + wc * 64 + j * 16 + lr;
        float v = acc[i][j][r];
        if (EPI == 0) {
          outb[(size_t)row * Ndim + col] = f2bf(v);
        } else if (EPI == 1) {
          v += bias[col];
          v = 0.5f * v * (1.0f + erff(v * 0.70710678118654752f));
          outb[(size_t)row * Ndim + col] = f2bf(v);
        } else {
          v = resid[(size_t)row * Ndim + col] + (v + bias[col]) * gamma[col];
          outf[(size_t)row * Ndim + col] = v;
        }
      }
}

// ---------------- fused attention: QK^T -> softmax -> attn out + PV ----------------
// grid (32 row-blocks, 64 bh). Per block: 32 Q rows, full K/V head.
// LDS: sK 1024x64 bf16 swizzled (128KB) | sQ 32x64 (4KB) at +131072
// after S: sP 32x1024 bf16 (64KB, overlays sK) | sVT 64x128 (16KB at +65536)
__global__ __launch_bounds__(256) void k_attn(const unsigned short* __restrict__ qkv,
                                              float* __restrict__ attn_out,
                                              unsigned short* __restrict__ ao) {
  __shared__ __align__(16) char smem[135168];
  __shared__ float red[2][4][32];

  const int tid = threadIdx.x;
  const int wid = tid >> 6, lane = tid & 63;
  const int lr = lane & 15, lhi = lane >> 4;
  const int q0 = blockIdx.x * 32;
  const int bh = blockIdx.y;
  const int b = bh >> 4, h = bh & 15;
  const size_t row0 = (size_t)(b * 1024) * 3072;
  const int hcol = h * 64;

  // ---- stage K (1024x64) and Q (32x64), XOR-swizzled ----
  {
    const int m0 = tid >> 3;
    const int d8 = (tid & 7) * 8;
#pragma unroll
    for (int r = 0; r < 32; ++r) {
      int m = r * 32 + m0;
      bf16x8 v = *(const bf16x8*)&qkv[row0 + (size_t)m * 3072 + 1024 + hcol + d8];
      *(bf16x8*)(smem + m * 128 + ((d8 * 2) ^ ((m & 7) << 4))) = v;
    }
    bf16x8 v = *(const bf16x8*)&qkv[row0 + (size_t)(q0 + m0) * 3072 + hcol + d8];
    *(bf16x8*)(smem + 131072 + m0 * 128 + ((d8 * 2) ^ ((m0 & 7) << 4))) = v;
  }
  __syncthreads();

  // ---- S = Q K^T : wave covers cols [wid*256, wid*256+256) ----
  f32x4 acc[2][16] = {};
#pragma unroll
  for (int kk = 0; kk < 2; ++kk) {
    bf16x8 a0, a1;
    {
      int r0 = lr;
      a0 = *(const bf16x8*)(smem + 131072 + r0 * 128 + ((kk * 64 + lhi * 16) ^ ((r0 & 7) << 4)));
      int r1 = 16 + lr;
      a1 = *(const bf16x8*)(smem + 131072 + r1 * 128 + ((kk * 64 + lhi * 16) ^ ((r1 & 7) << 4)));
    }
#pragma unroll
    for (int j = 0; j < 16; ++j) {
      int m = wid * 256 + j * 16 + lr;
      bf16x8 bv = *(const bf16x8*)(smem + m * 128 + ((kk * 64 + lhi * 16) ^ ((m & 7) << 4)));
      acc[0][j] = MFMA16(a0, bv, acc[0][j]);
      acc[1][j] = MFMA16(a1, bv, acc[1][j]);
    }
  }

  // ---- softmax over full row (scale=1/8) ----
  float mx[2][4], sm[2][4];
#pragma unroll
  for (int i = 0; i < 2; ++i)
#pragma unroll
    for (int r = 0; r < 4; ++r) {
      float m_ = -1e30f;
#pragma unroll
      for (int j = 0; j < 16; ++j) {
        acc[i][j][r] *= 0.125f;
        m_ = fmaxf(m_, acc[i][j][r]);
      }
#pragma unroll
      for (int off = 1; off < 16; off <<= 1) m_ = fmaxf(m_, __shfl_xor(m_, off));
      mx[i][r] = m_;
    }
  if (lr == 0) {
#pragma unroll
    for (int i = 0; i < 2; ++i)
#pragma unroll
      for (int r = 0; r < 4; ++r) red[0][wid][i * 16 + lhi * 4 + r] = mx[i][r];
  }
  __syncthreads();  // also: all sK/sQ reads complete past this point
#pragma unroll
  for (int i = 0; i < 2; ++i)
#pragma unroll
    for (int r = 0; r < 4; ++r) {
      int rl = i * 16 + lhi * 4 + r;
      float m_ = fmaxf(fmaxf(red[0][0][rl], red[0][1][rl]),
                       fmaxf(red[0][2][rl], red[0][3][rl]));
      float s_ = 0.f;
#pragma unroll
      for (int j = 0; j < 16; ++j) {
        float e = __expf(acc[i][j][r] - m_);
        acc[i][j][r] = e;
        s_ += e;
      }
#pragma unroll
      for (int off = 1; off < 16; off <<= 1) s_ += __shfl_xor(s_, off);
      sm[i][r] = s_;
    }
  if (lr == 0) {
#pragma unroll
    for (int i = 0; i < 2; ++i)
#pragma unroll
      for (int r = 0; r < 4; ++r) red[1][wid][i * 16 + lhi * 4 + r] = sm[i][r];
  }
  __syncthreads();

  // ---- normalize, write P bf16 to sP (overlays sK, swizzled rows of 2048B) ----
#pragma unroll
  for (int i = 0; i < 2; ++i)
#pragma unroll
    for (int r = 0; r < 4; ++r) {
      int rl = i * 16 + lhi * 4 + r;
      float inv = 1.0f / (red[1][0][rl] + red[1][1][rl] + red[1][2][rl] + red[1][3][rl]);
#pragma unroll
      for (int j = 0; j < 16; ++j) {
        int col = wid * 256 + j * 16 + lr;
        *(unsigned short*)(smem + rl * 2048 + ((col * 2) ^ ((rl & 7) << 4))) =
            f2bf(acc[i][j][r] * inv);
      }
    }
  __syncthreads();

  // ---- coalesced f32 attn store from sP ----
  {
    const size_t attn_base = (size_t)bh * 1024 * 1024 + (size_t)q0 * 1024;
#pragma unroll
    for (int r = 0; r < 32; ++r) {
      int idx = (r * 256 + tid) * 4;
      int row = idx >> 10, col = idx & 1023;
      bf16x4 p = *(const bf16x4*)(smem + row * 2048 + ((col * 2) ^ ((row & 7) << 4)));
      float4 o;
      o.x = bf2f((unsigned short)p[0]);
      o.y = bf2f((unsigned short)p[1]);
      o.z = bf2f((unsigned short)p[2]);
      o.w = bf2f((unsigned short)p[3]);
      *(float4*)&attn_out[attn_base + idx] = o;
    }
  }

  // ---- PV: ao[32,64] = P[32,1024] @ V[1024,64]; V tiles transposed into sVT ----
  f32x4 oacc[2] = {};
  for (int mt = 0; mt < 8; ++mt) {
    __syncthreads();  // protect sVT from previous tile's readers
    {
      const int m0 = tid >> 3;
      const int d8 = (tid & 7) * 8;
#pragma unroll
      for (int r2 = 0; r2 < 4; ++r2) {
        int ml = r2 * 32 + m0;
        bf16x8 v = *(const bf16x8*)&qkv[row0 + (size_t)(mt * 128 + ml) * 3072 + 2048 + hcol + d8];
#pragma unroll
        for (int e = 0; e < 8; ++e) {
          int d = d8 + e;
          *(unsigned short*)(smem + 65536 + d * 256 + ((ml * 2) ^ ((d & 7) << 4))) =
              (unsigned short)v[e];
        }
      }
    }
    __syncthreads();
#pragma unroll
    for (int kk = 0; kk < 4; ++kk) {
      int n0 = lr, n1 = 16 + lr;
      bf16x8 a0 = *(const bf16x8*)(smem + n0 * 2048 +
                                   ((mt * 256 + kk * 64 + lhi * 16) ^ ((n0 & 7) << 4)));
      bf16x8 a1 = *(const bf16x8*)(smem + n1 * 2048 +
                                   ((mt * 256 + kk * 64 + lhi * 16) ^ ((n1 & 7) << 4)));
      int d = wid * 16 + lr;
      bf16x8 bv = *(const bf16x8*)(smem + 65536 + d * 256 +
                                   ((kk * 64 + lhi * 16) ^ ((d & 7) << 4)));
      oacc[0] = MFMA16(a0, bv, oacc[0]);
      oacc[1] = MFMA16(a1, bv, oacc[1]);
    }
  }
#pragma unroll
  for (int i = 0; i < 2; ++i)
#pragma unroll
    for (int r = 0; r < 4; ++r) {
      int n = q0 + i * 16 + lhi * 4 + r;
      int d = hcol + wid * 16 + lr;
      ao[(size_t)(b * 1024 + n) * 1024 + d] = f2bf(oacc[i][r]);
    }
}

// ---------------- launch ----------------
extern "C" void kernel_launch(void* const* d_in, const int* in_sizes, int n_in,
                              void* d_out, int out_size, void* d_ws, size_t ws_size,
                              hipStream_t stream) {
  (void)in_sizes; (void)n_in; (void)out_size; (void)ws_size;
  const float* x     = (const float*)d_in[0];
  const float* ln1g  = (const float*)d_in[1];
  const float* ln1b  = (const float*)d_in[2];
  const float* qkvw  = (const float*)d_in[3];
  const float* projw = (const float*)d_in[4];
  const float* projb = (const float*)d_in[5];
  const float* g1    = (const float*)d_in[6];
  const float* ln2g  = (const float*)d_in[7];
  const float* ln2b  = (const float*)d_in[8];
  const float* fc1w  = (const float*)d_in[9];
  const float* fc1b  = (const float*)d_in[10];
  const float* fc2w  = (const float*)d_in[11];
  const float* fc2b  = (const float*)d_in[12];
  const float* g2    = (const float*)d_in[13];

  char* ws = (char*)d_ws;
  unsigned short* w_qkv  = (unsigned short*)(ws);              // 6 MB
  unsigned short* w_proj = (unsigned short*)(ws + 6291456);    // 2 MB
  unsigned short* w_fc1  = (unsigned short*)(ws + 8388608);    // 8 MB
  unsigned short* w_fc2  = (unsigned short*)(ws + 16777216);   // 8 MB
  unsigned short* n12    = (unsigned short*)(ws + 25165824);   // 8 MB (n1, later n2)
  unsigned short* qkvb   = (unsigned short*)(ws + 33554432);   // 24 MB (later h: 32 MB)
  unsigned short* hbuf   = qkvb;                               // h overlays qkv+ao (both dead)
  unsigned short* aob    = (unsigned short*)(ws + 58720256);   // 8 MB
  float*          x1     = (float*)(ws + 67108864);            // 16 MB  (total 80 MB)

  float* outx = (float*)d_out;
  float* outattn = outx + (size_t)4096 * 1024;

  k_cvt<<<3072, 256, 0, stream>>>(qkvw, w_qkv);
  k_cvt<<<1024, 256, 0, stream>>>(projw, w_proj);
  k_cvt<<<4096, 256, 0, stream>>>(fc1w, w_fc1);
  k_cvt<<<4096, 256, 0, stream>>>(fc2w, w_fc2);

  k_ln<<<4096, 256, 0, stream>>>(x, ln1g, ln1b, n12);
  k_gemm_bt<0><<<dim3(24, 32), 256, 0, stream>>>(n12, w_qkv, 3072, 1024,
                                                 nullptr, nullptr, nullptr, qkvb, nullptr);
  k_attn<<<dim3(32, 64), 256, 0, stream>>>(qkvb, outattn, aob);
  k_gemm_bt<2><<<dim3(8, 32), 256, 0, stream>>>(aob, w_proj, 1024, 1024,
                                                projb, g1, x, nullptr, x1);
  k_ln<<<4096, 256, 0, stream>>>(x1, ln2g, ln2b, n12);
  k_gemm_bt<1><<<dim3(32, 32), 256, 0, stream>>>(n12, w_fc1, 4096, 1024,
                                                 fc1b, nullptr, nullptr, hbuf, nullptr);
  k_gemm_bt<2><<<dim3(8, 32), 256, 0, stream>>>(hbuf, w_fc2, 1024, 4096,
                                                fc2b, g2, x1, nullptr, outx);
}

// Round 2
// 410.620 us; speedup vs baseline: 1.1396x; 1.1396x over previous
//
#include <hip/hip_runtime.h>
#include <math.h>

// ---------------- types / helpers ----------------
typedef __attribute__((ext_vector_type(8))) short bf16x8;
typedef __attribute__((ext_vector_type(4))) short bf16x4;
typedef __attribute__((ext_vector_type(4))) float f32x4;

__device__ __forceinline__ unsigned short f2bf(float f) {
  unsigned u = __builtin_bit_cast(unsigned, f);
  u += 0x7fffu + ((u >> 16) & 1u);           // RNE
  return (unsigned short)(u >> 16);
}

#define MFMA16(a, b, c) __builtin_amdgcn_mfma_f32_16x16x32_bf16((a), (b), (c), 0, 0, 0)

__device__ __forceinline__ void gload_lds16(const void* g, void* l) {
  __builtin_amdgcn_global_load_lds(
      (const __attribute__((address_space(1))) unsigned*)g,
      (__attribute__((address_space(3))) unsigned*)l, 16, 0, 0);
}

// ---------------- fp32 -> bf16 convert (weights) ----------------
__global__ __launch_bounds__(256) void k_cvt(const float* __restrict__ in,
                                             unsigned short* __restrict__ out) {
  int i = blockIdx.x * 256 + threadIdx.x;
  float4 v = ((const float4*)in)[i];
  bf16x4 o;
  o[0] = (short)f2bf(v.x); o[1] = (short)f2bf(v.y);
  o[2] = (short)f2bf(v.z); o[3] = (short)f2bf(v.w);
  *(bf16x4*)(out + (size_t)i * 4) = o;
}

// ---------------- layernorm (1024 cols, 1 block/row) -> bf16 ----------------
__global__ __launch_bounds__(256) void k_ln(const float* __restrict__ x,
                                            const float* __restrict__ g,
                                            const float* __restrict__ b,
                                            unsigned short* __restrict__ out) {
  __shared__ float red[8];
  const int tid = threadIdx.x;
  const size_t row = blockIdx.x;
  float4 v = ((const float4*)(x + row * 1024))[tid];
  float s = v.x + v.y + v.z + v.w;
#pragma unroll
  for (int off = 32; off; off >>= 1) s += __shfl_xor(s, off);
  if ((tid & 63) == 0) red[tid >> 6] = s;
  __syncthreads();
  float mu = (red[0] + red[1] + red[2] + red[3]) * (1.0f / 1024.0f);
  float dx = v.x - mu, dy = v.y - mu, dz = v.z - mu, dw = v.w - mu;
  float s2 = dx * dx + dy * dy + dz * dz + dw * dw;
#pragma unroll
  for (int off = 32; off; off >>= 1) s2 += __shfl_xor(s2, off);
  if ((tid & 63) == 0) red[4 + (tid >> 6)] = s2;
  __syncthreads();
  float var = (red[4] + red[5] + red[6] + red[7]) * (1.0f / 1024.0f);
  float rstd = rsqrtf(var + 1e-5f);
  float4 gv = ((const float4*)g)[tid];
  float4 bv = ((const float4*)b)[tid];
  bf16x4 o;
  o[0] = (short)f2bf(dx * rstd * gv.x + bv.x);
  o[1] = (short)f2bf(dy * rstd * gv.y + bv.y);
  o[2] = (short)f2bf(dz * rstd * gv.z + bv.z);
  o[3] = (short)f2bf(dw * rstd * gv.w + bv.w);
  *(bf16x4*)(out + row * 1024 + tid * 4) = o;
}

// ---------------- bt-GEMM (m97 structure): C[M,N] = A[M,K] @ B[N,K]^T ----------------
// EPI 0: store bf16
// EPI 1: v += bias[col]; v = gelu_exact(v); store bf16
// EPI 2: v = resid[row,col] + (v + bias[col]) * gamma[col]; store f32
template <int EPI>
__global__ __launch_bounds__(256) void k_gemm_bt(
    const unsigned short* __restrict__ A, const unsigned short* __restrict__ Bw,
    int Ndim, int K,
    const float* __restrict__ bias, const float* __restrict__ gamma,
    const float* __restrict__ resid,
    unsigned short* __restrict__ outb, float* __restrict__ outf) {
  __shared__ __align__(16) unsigned short sA[128 * 64];
  __shared__ __align__(16) unsigned short sB[128 * 64];
  const int tid = threadIdx.x;
  const int wid = tid >> 6, lane = tid & 63;
  const int wr = wid >> 1, wc = wid & 1;
  const int lr = lane & 15, lhi = lane >> 4;
  const int brow = blockIdx.y, bcol = blockIdx.x;

  const size_t a_base = (size_t)brow * 128 * K;
  const size_t b_base = (size_t)bcol * 128 * K;
  const int srow = tid >> 3;       // 0..31
  const int scol = (tid & 7) * 8;  // 0..56

  f32x4 acc[4][4] = {};

  for (int k0 = 0; k0 < K; k0 += 64) {
    __syncthreads();  // previous iteration's readers done
#pragma unroll
    for (int r = 0; r < 4; ++r) {
      int row = r * 32 + srow;
      gload_lds16(&A[a_base + (size_t)row * K + k0 + scol], &sA[row * 64 + scol]);
      gload_lds16(&Bw[b_base + (size_t)row * K + k0 + scol], &sB[row * 64 + scol]);
    }
    __syncthreads();  // drains vmcnt (compiler emits vmcnt(0) before barrier)
#pragma unroll
    for (int kk = 0; kk < 2; ++kk) {
      bf16x8 af[4], bfr[4];
#pragma unroll
      for (int i = 0; i < 4; ++i) {
        int ar = wr * 64 + i * 16 + lr;
        af[i] = *(const bf16x8*)&sA[ar * 64 + kk * 32 + lhi * 8];
        int br = wc * 64 + i * 16 + lr;
        bfr[i] = *(const bf16x8*)&sB[br * 64 + kk * 32 + lhi * 8];
      }
#pragma unroll
      for (int i = 0; i < 4; ++i)
#pragma unroll
        for (int j = 0; j < 4; ++j)
          acc[i][j] = MFMA16(af[i], bfr[j], acc[i][j]);
    }
  }

#pragma unroll
  for (int i = 0; i < 4; ++i)
#pragma unroll
    for (int j = 0; j < 4; ++j)
#pragma unroll
      for (int r = 0; r < 4; ++r) {
        int row = brow * 128 + wr * 64 + i * 16 + lhi * 4 + r;
        int col = bcol * 128 + wc * 64 + j * 16 + lr;
        float v = acc[i][j][r];
        if (EPI == 0) {
          outb[(size_t)row * Ndim + col] = f2bf(v);
        } else if (EPI == 1) {
          v += bias[col];
          v = 0.5f * v * (1.0f + erff(v * 0.70710678118654752f));
          outb[(size_t)row * Ndim + col] = f2bf(v);
        } else {
          v = resid[(size_t)row * Ndim + col] + (v + bias[col]) * gamma[col];
          outf[(size_t)row * Ndim + col] = v;
        }
      }
}

// ---------------- fused attention v2 ----------------
// grid (32 q-blocks, 64 bh), 256 threads. Wave w owns kv slice [w*256, w*256+256).
// No K/Q LDS staging (direct global->reg fragments, L2-served).
// S in regs, softmax in regs + tiny red LDS, attn f32 stored from regs.
// PV: per-wave private LDS (sP 4KB + VT 8KB, 64-kv sub-tiles), barrier-free;
// ao^T = mfma(VT_frag, P_frag); cross-wave f32 reduce at the end.
__global__ __launch_bounds__(256) void k_attn(const unsigned short* __restrict__ qkv,
                                              float* __restrict__ attn_out,
                                              unsigned short* __restrict__ ao) {
  __shared__ __align__(16) char smem[49152];  // sP 16K | sVT 32K ; sAO 33280 overlays
  __shared__ float red[2][4][32];

  const int tid = threadIdx.x;
  const int wid = tid >> 6, lane = tid & 63;
  const int lr = lane & 15, lhi = lane >> 4;
  const int q0 = blockIdx.x * 32;
  const int bh = blockIdx.y;
  const int b = bh >> 4, h = bh & 15;
  const size_t row0 = (size_t)b * 1024 * 3072;
  const int hcol = h * 64;

  // ---- Q fragments direct from global ----
  bf16x8 af[2][2];
#pragma unroll
  for (int i = 0; i < 2; ++i)
#pragma unroll
    for (int kk = 0; kk < 2; ++kk)
      af[i][kk] = *(const bf16x8*)&qkv[row0 + (size_t)(q0 + i * 16 + lr) * 3072 +
                                       hcol + kk * 32 + lhi * 8];

  // ---- S = Q K^T : wave covers kv [wid*256, +256) ----
  f32x4 acc[2][16] = {};
#pragma unroll
  for (int kk = 0; kk < 2; ++kk) {
#pragma unroll
    for (int j = 0; j < 16; ++j) {
      int m = wid * 256 + j * 16 + lr;
      bf16x8 bv = *(const bf16x8*)&qkv[row0 + (size_t)m * 3072 + 1024 +
                                       hcol + kk * 32 + lhi * 8];
      acc[0][j] = MFMA16(af[0][kk], bv, acc[0][j]);
      acc[1][j] = MFMA16(af[1][kk], bv, acc[1][j]);
    }
  }

  // ---- softmax (scale = 1/8) ----
  float mx[2][4], sm[2][4];
#pragma unroll
  for (int i = 0; i < 2; ++i)
#pragma unroll
    for (int r = 0; r < 4; ++r) {
      float m_ = -1e30f;
#pragma unroll
      for (int j = 0; j < 16; ++j) {
        acc[i][j][r] *= 0.125f;
        m_ = fmaxf(m_, acc[i][j][r]);
      }
#pragma unroll
      for (int off = 1; off < 16; off <<= 1) m_ = fmaxf(m_, __shfl_xor(m_, off));
      mx[i][r] = m_;
    }
  if (lr == 0) {
#pragma unroll
    for (int i = 0; i < 2; ++i)
#pragma unroll
      for (int r = 0; r < 4; ++r) red[0][wid][i * 16 + lhi * 4 + r] = mx[i][r];
  }
  __syncthreads();
#pragma unroll
  for (int i = 0; i < 2; ++i)
#pragma unroll
    for (int r = 0; r < 4; ++r) {
      int rl = i * 16 + lhi * 4 + r;
      float m_ = fmaxf(fmaxf(red[0][0][rl], red[0][1][rl]),
                       fmaxf(red[0][2][rl], red[0][3][rl]));
      float s_ = 0.f;
#pragma unroll
      for (int j = 0; j < 16; ++j) {
        float e = __expf(acc[i][j][r] - m_);
        acc[i][j][r] = e;
        s_ += e;
      }
#pragma unroll
      for (int off = 1; off < 16; off <<= 1) s_ += __shfl_xor(s_, off);
      sm[i][r] = s_;
    }
  if (lr == 0) {
#pragma unroll
    for (int i = 0; i < 2; ++i)
#pragma unroll
      for (int r = 0; r < 4; ++r) red[1][wid][i * 16 + lhi * 4 + r] = sm[i][r];
  }
  __syncthreads();

  float inv[2][4];
#pragma unroll
  for (int i = 0; i < 2; ++i)
#pragma unroll
    for (int r = 0; r < 4; ++r) {
      int rl = i * 16 + lhi * 4 + r;
      inv[i][r] = 1.0f / (red[1][0][rl] + red[1][1][rl] + red[1][2][rl] + red[1][3][rl]);
    }

  // ---- normalize: store attn f32 from regs + pack P to bf16 regs ----
  unsigned pb[2][16][2];
  {
    const size_t attn_base =
        (size_t)bh * 1024 * 1024 + ((size_t)q0) * 1024 + (size_t)(wid * 256);
#pragma unroll
    for (int i = 0; i < 2; ++i)
#pragma unroll
      for (int j = 0; j < 16; ++j) {
        float p0 = acc[i][j][0] * inv[i][0];
        float p1 = acc[i][j][1] * inv[i][1];
        float p2 = acc[i][j][2] * inv[i][2];
        float p3 = acc[i][j][3] * inv[i][3];
        size_t base = attn_base + (size_t)(i * 16 + lhi * 4) * 1024 + j * 16 + lr;
        attn_out[base] = p0;
        attn_out[base + 1024] = p1;
        attn_out[base + 2048] = p2;
        attn_out[base + 3072] = p3;
        pb[i][j][0] = (unsigned)f2bf(p0) | ((unsigned)f2bf(p1) << 16);
        pb[i][j][1] = (unsigned)f2bf(p2) | ((unsigned)f2bf(p3) << 16);
      }
  }

  // ---- PV per wave over private LDS, 4 sub-tiles of 64 kv ----
  char* sP = smem + wid * 4096;           // [32 q][64 kv] bf16, swizzled rows of 128B
  char* sV = smem + 16384 + wid * 8192;   // VT [64 d][64 kv] bf16, swizzled rows of 128B
  f32x4 oaccT[4][2] = {};                 // [dt][qt], D[d][q]

#pragma unroll
  for (int t = 0; t < 4; ++t) {
    // (a) write sP sub-tile from pb
#pragma unroll
    for (int i = 0; i < 2; ++i)
#pragma unroll
      for (int jl = 0; jl < 4; ++jl) {
        int j = t * 4 + jl;
        int kvl2 = (jl * 16 + lr) * 2;
#pragma unroll
        for (int hp = 0; hp < 2; ++hp) {
          unsigned d = pb[i][j][hp];
          int qa = i * 16 + lhi * 4 + hp * 2;
          int qb = qa + 1;
          *(unsigned short*)(sP + qa * 128 + (kvl2 ^ ((qa & 7) << 4))) =
              (unsigned short)(d & 0xffff);
          *(unsigned short*)(sP + qb * 128 + (kvl2 ^ ((qb & 7) << 4))) =
              (unsigned short)(d >> 16);
        }
      }
    // (b) stage V transposed: paired-row b32 writes (conflict-free)
    {
      int kvq = lane >> 2;           // 0..15
      int dq = (lane & 3) * 8;
#pragma unroll
      for (int rt = 0; rt < 2; ++rt)
#pragma unroll
        for (int dh = 0; dh < 2; ++dh) {
          int kvp2 = rt * 16 + kvq;  // pair index 0..31
          int kvg = wid * 256 + t * 64 + kvp2 * 2;
          int d0 = dh * 32 + dq;
          bf16x8 v0 = *(const bf16x8*)&qkv[row0 + (size_t)kvg * 3072 + 2048 + hcol + d0];
          bf16x8 v1 = *(const bf16x8*)&qkv[row0 + (size_t)(kvg + 1) * 3072 + 2048 + hcol + d0];
#pragma unroll
          for (int e = 0; e < 8; ++e) {
            int d = d0 + e;
            unsigned dw = (unsigned)(unsigned short)v0[e] |
                          ((unsigned)(unsigned short)v1[e] << 16);
            *(unsigned*)(sV + d * 128 + ((kvp2 * 4) ^ ((d & 7) << 4))) = dw;
          }
        }
    }
    // (c) ao^T += VT_frag * P_frag   (wave-private LDS: no barrier needed)
#pragma unroll
    for (int c = 0; c < 2; ++c) {
      bf16x8 pf[2];
#pragma unroll
      for (int qt = 0; qt < 2; ++qt) {
        int q_ = qt * 16 + lr;
        pf[qt] = *(const bf16x8*)(sP + q_ * 128 + ((c * 64 + lhi * 16) ^ ((q_ & 7) << 4)));
      }
#pragma unroll
      for (int dt = 0; dt < 4; ++dt) {
        int d_ = dt * 16 + lr;
        bf16x8 vf = *(const bf16x8*)(sV + d_ * 128 + ((c * 64 + lhi * 16) ^ ((d_ & 7) << 4)));
        oaccT[dt][0] = MFMA16(vf, pf[0], oaccT[dt][0]);
        oaccT[dt][1] = MFMA16(vf, pf[1], oaccT[dt][1]);
      }
    }
  }

  // ---- cross-wave reduce of ao partials ----
  __syncthreads();  // everyone done with sP/sV before overlaying sAO
  float* sAO = (float*)smem;  // [4][32 q][65] f32 (stride 65 breaks conflicts)
#pragma unroll
  for (int dt = 0; dt < 4; ++dt)
#pragma unroll
    for (int qt = 0; qt < 2; ++qt)
#pragma unroll
      for (int r = 0; r < 4; ++r) {
        int q_ = qt * 16 + lr;
        int d_ = dt * 16 + lhi * 4 + r;
        sAO[wid * 2080 + q_ * 65 + d_] = oaccT[dt][qt][r];
      }
  __syncthreads();
  {
    int q_ = tid >> 3;
    int d0 = (tid & 7) * 8;
    bf16x8 o;
#pragma unroll
    for (int e = 0; e < 8; ++e) {
      int d_ = d0 + e;
      float s = sAO[q_ * 65 + d_] + sAO[2080 + q_ * 65 + d_] +
                sAO[4160 + q_ * 65 + d_] + sAO[6240 + q_ * 65 + d_];
      o[e] = (short)f2bf(s);
    }
    *(bf16x8*)&ao[(size_t)(b * 1024 + q0 + q_) * 1024 + hcol + d0] = o;
  }
}

// ---------------- launch ----------------
extern "C" void kernel_launch(void* const* d_in, const int* in_sizes, int n_in,
                              void* d_out, int out_size, void* d_ws, size_t ws_size,
                              hipStream_t stream) {
  (void)in_sizes; (void)n_in; (void)out_size; (void)ws_size;
  const float* x     = (const float*)d_in[0];
  const float* ln1g  = (const float*)d_in[1];
  const float* ln1b  = (const float*)d_in[2];
  const float* qkvw  = (const float*)d_in[3];
  const float* projw = (const float*)d_in[4];
  const float* projb = (const float*)d_in[5];
  const float* g1    = (const float*)d_in[6];
  const float* ln2g  = (const float*)d_in[7];
  const float* ln2b  = (const float*)d_in[8];
  const float* fc1w  = (const float*)d_in[9];
  const float* fc1b  = (const float*)d_in[10];
  const float* fc2w  = (const float*)d_in[11];
  const float* fc2b  = (const float*)d_in[12];
  const float* g2    = (const float*)d_in[13];

  char* ws = (char*)d_ws;
  unsigned short* w_qkv  = (unsigned short*)(ws);              // 6 MB
  unsigned short* w_proj = (unsigned short*)(ws + 6291456);    // 2 MB
  unsigned short* w_fc1  = (unsigned short*)(ws + 8388608);    // 8 MB
  unsigned short* w_fc2  = (unsigned short*)(ws + 16777216);   // 8 MB
  unsigned short* n12    = (unsigned short*)(ws + 25165824);   // 8 MB (n1, later n2)
  unsigned short* qkvb   = (unsigned short*)(ws + 33554432);   // 24 MB (later h: 32 MB)
  unsigned short* hbuf   = qkvb;                               // h overlays qkv (dead)
  unsigned short* aob    = (unsigned short*)(ws + 58720256);   // 8 MB
  float*          x1     = (float*)(ws + 67108864);            // 16 MB

  float* outx = (float*)d_out;
  float* outattn = outx + (size_t)4096 * 1024;

  k_cvt<<<3072, 256, 0, stream>>>(qkvw, w_qkv);
  k_cvt<<<1024, 256, 0, stream>>>(projw, w_proj);
  k_cvt<<<4096, 256, 0, stream>>>(fc1w, w_fc1);
  k_cvt<<<4096, 256, 0, stream>>>(fc2w, w_fc2);

  k_ln<<<4096, 256, 0, stream>>>(x, ln1g, ln1b, n12);
  k_gemm_bt<0><<<dim3(24, 32), 256, 0, stream>>>(n12, w_qkv, 3072, 1024,
                                                 nullptr, nullptr, nullptr, qkvb, nullptr);
  k_attn<<<dim3(32, 64), 256, 0, stream>>>(qkvb, outattn, aob);
  k_gemm_bt<2><<<dim3(8, 32), 256, 0, stream>>>(aob, w_proj, 1024, 1024,
                                                projb, g1, x, nullptr, x1);
  k_ln<<<4096, 256, 0, stream>>>(x1, ln2g, ln2b, n12);
  k_gemm_bt<1><<<dim3(32, 32), 256, 0, stream>>>(n12, w_fc1, 4096, 1024,
                                                 fc1b, nullptr, nullptr, hbuf, nullptr);
  k_gemm_bt<2><<<dim3(8, 32), 256, 0, stream>>>(hbuf, w_fc2, 1024, 4096,
                                                fc2b, g2, x1, nullptr, outx);
}

// Round 3
// 377.432 us; speedup vs baseline: 1.2398x; 1.0879x over previous
//
#include <hip/hip_runtime.h>
#include <math.h>

// ---------------- types / helpers ----------------
typedef __attribute__((ext_vector_type(8))) short bf16x8;
typedef __attribute__((ext_vector_type(4))) short bf16x4;
typedef __attribute__((ext_vector_type(4))) float f32x4;

__device__ __forceinline__ unsigned short f2bf(float f) {
  unsigned u = __builtin_bit_cast(unsigned, f);
  u += 0x7fffu + ((u >> 16) & 1u);           // RNE
  return (unsigned short)(u >> 16);
}

#define MFMA16(a, b, c) __builtin_amdgcn_mfma_f32_16x16x32_bf16((a), (b), (c), 0, 0, 0)

__device__ __forceinline__ void gload_lds16(const void* g, void* l) {
  __builtin_amdgcn_global_load_lds(
      (const __attribute__((address_space(1))) unsigned*)g,
      (__attribute__((address_space(3))) unsigned*)l, 16, 0, 0);
}

// bijective XCD swizzle (m204)
__device__ __forceinline__ int xcd_swz(int bid, int nwg) {
  int q = nwg >> 3, r = nwg & 7;
  int xcd = bid & 7, off = bid >> 3;
  return (xcd < r ? xcd * (q + 1) : r * (q + 1) + (xcd - r) * q) + off;
}

// ---------------- fused fp32 -> bf16 convert (all 4 weights) ----------------
__global__ __launch_bounds__(256) void k_cvt4(
    const float* __restrict__ wq, const float* __restrict__ wp,
    const float* __restrict__ w1, const float* __restrict__ w2,
    unsigned short* __restrict__ oq, unsigned short* __restrict__ op,
    unsigned short* __restrict__ o1, unsigned short* __restrict__ o2) {
  int bid = blockIdx.x;
  const float* src; unsigned short* dst; int base;
  if (bid < 3072)      { src = wq; dst = oq; base = bid; }
  else if (bid < 4096) { src = wp; dst = op; base = bid - 3072; }
  else if (bid < 8192) { src = w1; dst = o1; base = bid - 4096; }
  else                 { src = w2; dst = o2; base = bid - 8192; }
  int i = base * 256 + threadIdx.x;
  float4 v = ((const float4*)src)[i];
  bf16x4 o;
  o[0] = (short)f2bf(v.x); o[1] = (short)f2bf(v.y);
  o[2] = (short)f2bf(v.z); o[3] = (short)f2bf(v.w);
  *(bf16x4*)(dst + (size_t)i * 4) = o;
}

// ---------------- layernorm (1024 cols, 1 block/row) -> bf16 ----------------
__global__ __launch_bounds__(256) void k_ln(const float* __restrict__ x,
                                            const float* __restrict__ g,
                                            const float* __restrict__ b,
                                            unsigned short* __restrict__ out) {
  __shared__ float red[8];
  const int tid = threadIdx.x;
  const size_t row = blockIdx.x;
  float4 v = ((const float4*)(x + row * 1024))[tid];
  float s = v.x + v.y + v.z + v.w;
#pragma unroll
  for (int off = 32; off; off >>= 1) s += __shfl_xor(s, off);
  if ((tid & 63) == 0) red[tid >> 6] = s;
  __syncthreads();
  float mu = (red[0] + red[1] + red[2] + red[3]) * (1.0f / 1024.0f);
  float dx = v.x - mu, dy = v.y - mu, dz = v.z - mu, dw = v.w - mu;
  float s2 = dx * dx + dy * dy + dz * dz + dw * dw;
#pragma unroll
  for (int off = 32; off; off >>= 1) s2 += __shfl_xor(s2, off);
  if ((tid & 63) == 0) red[4 + (tid >> 6)] = s2;
  __syncthreads();
  float var = (red[4] + red[5] + red[6] + red[7]) * (1.0f / 1024.0f);
  float rstd = rsqrtf(var + 1e-5f);
  float4 gv = ((const float4*)g)[tid];
  float4 bv = ((const float4*)b)[tid];
  bf16x4 o;
  o[0] = (short)f2bf(dx * rstd * gv.x + bv.x);
  o[1] = (short)f2bf(dy * rstd * gv.y + bv.y);
  o[2] = (short)f2bf(dz * rstd * gv.z + bv.z);
  o[3] = (short)f2bf(dw * rstd * gv.w + bv.w);
  *(bf16x4*)(out + row * 1024 + tid * 4) = o;
}

// ============ 256x256 multi-phase GEMM: C[M,N] = A[M,K] @ B[N,K]^T ============
// 512 thr = 8 waves (2M x 4N), per-wave 128x64, BK=64, 2 LDS buffers (128 KB).
// Phase P: vmcnt(6); barrier; ds_read half staged at P-4; stage S_P; lgkm; 16 MFMA.
// Half order per tile: Aeven, Beven, Aodd, Bodd (quadrant-aligned halves).
// MFMA skew: q0 computes (mh1,nh1) of PREVIOUS tile; q1 (mh0,nh0); q2 (mh1,nh0);
// q3 (mh0,nh1); final (mh1,nh1) after the loop.
// EPI 0: store bf16.  EPI 1: bias + exact GELU, store bf16.
template <int EPI>
__global__ __launch_bounds__(512, 2) void k_gemm256(
    const unsigned short* __restrict__ A, const unsigned short* __restrict__ Bw,
    int Ndim, int K, int nby,
    const float* __restrict__ bias,
    unsigned short* __restrict__ outb) {
  __shared__ __align__(16) unsigned short lds[2][2][16384];  // [buf][A|B][256*64]

  const int tid = threadIdx.x;
  const int wid = tid >> 6, lane = tid & 63;
  const int wm = wid >> 2, wn = wid & 3;
  const int lr = lane & 15, lhi = lane >> 4;

  const int nwg = gridDim.x;
  const int swz = xcd_swz(blockIdx.x, nwg);
  const int bcol = swz / nby, brow = swz % nby;

  const size_t a_base = (size_t)brow * 256 * K;
  const size_t b_base = (size_t)bcol * 256 * K;
  const int NT = K >> 6;

  // staging: this thread's 2 chunks of half `which` of tile kt -> buf dbuf
  auto STAGE = [&](int dbuf, int kt, int which) {
    int ktc = (kt < NT) ? kt : 0;
    int isB = which & 1;
    int odd = which >> 1;
    const unsigned short* src = isB ? (Bw + b_base) : (A + a_base);
    int col = (ktc << 6) + (((lane & 7) ^ ((lane >> 3) & 7)) << 3);
#pragma unroll
    for (int c = 0; c < 2; ++c) {
      int idx = (wid << 1) | c;
      int chunk = isB ? ((idx & 3) + ((idx >> 2) << 3) + (odd << 2))
                      : ((idx & 7) + ((idx >> 3) << 4) + (odd << 3));
      int row = (chunk << 3) + (lane >> 3);
      gload_lds16(src + (size_t)row * K + col,
                  &lds[dbuf][isB][chunk * 512 + lane * 8]);
    }
  };

  // prologue: stage tile 0 (4 halves) into buf0
  STAGE(0, 0, 0); STAGE(0, 0, 1); STAGE(0, 0, 2); STAGE(0, 0, 3);

  f32x4 acc[8][4] = {};
  bf16x8 aF0[4][2], aF1[4][2], bF0[2][2], bF1[2][2];

  const int colx0 = (lhi << 4) ^ ((lr & 7) << 4);
  const int colx1 = (64 + (lhi << 4)) ^ ((lr & 7) << 4);

  for (int t = 0; t < NT; ++t) {
    const int buf = t & 1;
    const char* sAb = (const char*)&lds[buf][0][0];
    const char* sBb = (const char*)&lds[buf][1][0];
#pragma unroll
    for (int q = 0; q < 4; ++q) {
      asm volatile("s_waitcnt vmcnt(6)" ::: "memory");
      __builtin_amdgcn_s_barrier();
      if (q == 0) {
#pragma unroll
        for (int m = 0; m < 4; ++m) {
          int ro = (wm * 128 + m * 16 + lr) * 128;
          aF0[m][0] = *(const bf16x8*)(sAb + ro + colx0);
          aF0[m][1] = *(const bf16x8*)(sAb + ro + colx1);
        }
      } else if (q == 1) {
#pragma unroll
        for (int n = 0; n < 2; ++n) {
          int ro = (wn * 64 + n * 16 + lr) * 128;
          bF0[n][0] = *(const bf16x8*)(sBb + ro + colx0);
          bF0[n][1] = *(const bf16x8*)(sBb + ro + colx1);
        }
      } else if (q == 2) {
#pragma unroll
        for (int m = 0; m < 4; ++m) {
          int ro = (wm * 128 + 64 + m * 16 + lr) * 128;
          aF1[m][0] = *(const bf16x8*)(sAb + ro + colx0);
          aF1[m][1] = *(const bf16x8*)(sAb + ro + colx1);
        }
      } else {
#pragma unroll
        for (int n = 0; n < 2; ++n) {
          int ro = (wn * 64 + 32 + n * 16 + lr) * 128;
          bF1[n][0] = *(const bf16x8*)(sBb + ro + colx0);
          bF1[n][1] = *(const bf16x8*)(sBb + ro + colx1);
        }
      }
      STAGE(buf ^ 1, t + 1, q);
      asm volatile("s_waitcnt lgkmcnt(0)" ::: "memory");
      __builtin_amdgcn_sched_barrier(0);
      __builtin_amdgcn_s_setprio(1);
      if (q == 0) {
        if (t > 0) {
#pragma unroll
          for (int m = 0; m < 4; ++m)
#pragma unroll
            for (int n = 0; n < 2; ++n)
#pragma unroll
              for (int kk = 0; kk < 2; ++kk)
                acc[4 + m][2 + n] = MFMA16(aF1[m][kk], bF1[n][kk], acc[4 + m][2 + n]);
        }
      } else if (q == 1) {
#pragma unroll
        for (int m = 0; m < 4; ++m)
#pragma unroll
          for (int n = 0; n < 2; ++n)
#pragma unroll
            for (int kk = 0; kk < 2; ++kk)
              acc[m][n] = MFMA16(aF0[m][kk], bF0[n][kk], acc[m][n]);
      } else if (q == 2) {
#pragma unroll
        for (int m = 0; m < 4; ++m)
#pragma unroll
          for (int n = 0; n < 2; ++n)
#pragma unroll
            for (int kk = 0; kk < 2; ++kk)
              acc[4 + m][n] = MFMA16(aF1[m][kk], bF0[n][kk], acc[4 + m][n]);
      } else {
#pragma unroll
        for (int m = 0; m < 4; ++m)
#pragma unroll
          for (int n = 0; n < 2; ++n)
#pragma unroll
            for (int kk = 0; kk < 2; ++kk)
              acc[m][2 + n] = MFMA16(aF0[m][kk], bF1[n][kk], acc[m][2 + n]);
      }
      __builtin_amdgcn_s_setprio(0);
    }
  }
  // final leftover quadrant of last tile
#pragma unroll
  for (int m = 0; m < 4; ++m)
#pragma unroll
    for (int n = 0; n < 2; ++n)
#pragma unroll
      for (int kk = 0; kk < 2; ++kk)
        acc[4 + m][2 + n] = MFMA16(aF1[m][kk], bF1[n][kk], acc[4 + m][2 + n]);

  // epilogue
#pragma unroll
  for (int m = 0; m < 8; ++m)
#pragma unroll
    for (int n = 0; n < 4; ++n) {
      int col = bcol * 256 + wn * 64 + n * 16 + lr;
      float bi = (EPI == 1) ? bias[col] : 0.0f;
#pragma unroll
      for (int r = 0; r < 4; ++r) {
        int row = brow * 256 + wm * 128 + m * 16 + lhi * 4 + r;
        float v = acc[m][n][r];
        if (EPI == 1) {
          v += bi;
          v = 0.5f * v * (1.0f + erff(v * 0.70710678118654752f));
        }
        outb[(size_t)row * Ndim + col] = f2bf(v);
      }
    }
}

// ---------------- 128x128 bt-GEMM (m97 structure), EPI 2 epilogue ----------------
// v = resid[row,col] + (v + bias[col]) * gamma[col]; store f32
__global__ __launch_bounds__(256) void k_gemm_bt2(
    const unsigned short* __restrict__ A, const unsigned short* __restrict__ Bw,
    int Ndim, int K, int nby,
    const float* __restrict__ bias, const float* __restrict__ gamma,
    const float* __restrict__ resid, float* __restrict__ outf) {
  __shared__ __align__(16) unsigned short sA[128 * 64];
  __shared__ __align__(16) unsigned short sB[128 * 64];
  const int tid = threadIdx.x;
  const int wid = tid >> 6, lane = tid & 63;
  const int wr = wid >> 1, wc = wid & 1;
  const int lr = lane & 15, lhi = lane >> 4;
  const int swz = xcd_swz(blockIdx.x, gridDim.x);
  const int bcol = swz / nby, brow = swz % nby;

  const size_t a_base = (size_t)brow * 128 * K;
  const size_t b_base = (size_t)bcol * 128 * K;
  const int srow = tid >> 3;
  const int scol = (tid & 7) * 8;

  f32x4 acc[4][4] = {};

  for (int k0 = 0; k0 < K; k0 += 64) {
    __syncthreads();
#pragma unroll
    for (int r = 0; r < 4; ++r) {
      int row = r * 32 + srow;
      gload_lds16(&A[a_base + (size_t)row * K + k0 + scol], &sA[row * 64 + scol]);
      gload_lds16(&Bw[b_base + (size_t)row * K + k0 + scol], &sB[row * 64 + scol]);
    }
    __syncthreads();
#pragma unroll
    for (int kk = 0; kk < 2; ++kk) {
      bf16x8 af[4], bfr[4];
#pragma unroll
      for (int i = 0; i < 4; ++i) {
        int ar = wr * 64 + i * 16 + lr;
        af[i] = *(const bf16x8*)&sA[ar * 64 + kk * 32 + lhi * 8];
        int br = wc * 64 + i * 16 + lr;
        bfr[i] = *(const bf16x8*)&sB[br * 64 + kk * 32 + lhi * 8];
      }
#pragma unroll
      for (int i = 0; i < 4; ++i)
#pragma unroll
        for (int j = 0; j < 4; ++j)
          acc[i][j] = MFMA16(af[i], bfr[j], acc[i][j]);
    }
  }

#pragma unroll
  for (int i = 0; i < 4; ++i)
#pragma unroll
    for (int j = 0; j < 4; ++j)
#pragma unroll
      for (int r = 0; r < 4; ++r) {
        int row = brow * 128 + wr * 64 + i * 16 + lhi * 4 + r;
        int col = bcol * 128 + wc * 64 + j * 16 + lr;
        float v = resid[(size_t)row * Ndim + col] + (acc[i][j][r] + bias[col]) * gamma[col];
        outf[(size_t)row * Ndim + col] = v;
      }
}

// ---------------- fused attention v2 (unchanged from round 2) ----------------
__global__ __launch_bounds__(256) void k_attn(const unsigned short* __restrict__ qkv,
                                              float* __restrict__ attn_out,
                                              unsigned short* __restrict__ ao) {
  __shared__ __align__(16) char smem[49152];
  __shared__ float red[2][4][32];

  const int tid = threadIdx.x;
  const int wid = tid >> 6, lane = tid & 63;
  const int lr = lane & 15, lhi = lane >> 4;
  const int q0 = blockIdx.x * 32;
  const int bh = blockIdx.y;
  const int b = bh >> 4, h = bh & 15;
  const size_t row0 = (size_t)b * 1024 * 3072;
  const int hcol = h * 64;

  bf16x8 af[2][2];
#pragma unroll
  for (int i = 0; i < 2; ++i)
#pragma unroll
    for (int kk = 0; kk < 2; ++kk)
      af[i][kk] = *(const bf16x8*)&qkv[row0 + (size_t)(q0 + i * 16 + lr) * 3072 +
                                       hcol + kk * 32 + lhi * 8];

  f32x4 acc[2][16] = {};
#pragma unroll
  for (int kk = 0; kk < 2; ++kk) {
#pragma unroll
    for (int j = 0; j < 16; ++j) {
      int m = wid * 256 + j * 16 + lr;
      bf16x8 bv = *(const bf16x8*)&qkv[row0 + (size_t)m * 3072 + 1024 +
                                       hcol + kk * 32 + lhi * 8];
      acc[0][j] = MFMA16(af[0][kk], bv, acc[0][j]);
      acc[1][j] = MFMA16(af[1][kk], bv, acc[1][j]);
    }
  }

  float mx[2][4], sm[2][4];
#pragma unroll
  for (int i = 0; i < 2; ++i)
#pragma unroll
    for (int r = 0; r < 4; ++r) {
      float m_ = -1e30f;
#pragma unroll
      for (int j = 0; j < 16; ++j) {
        acc[i][j][r] *= 0.125f;
        m_ = fmaxf(m_, acc[i][j][r]);
      }
#pragma unroll
      for (int off = 1; off < 16; off <<= 1) m_ = fmaxf(m_, __shfl_xor(m_, off));
      mx[i][r] = m_;
    }
  if (lr == 0) {
#pragma unroll
    for (int i = 0; i < 2; ++i)
#pragma unroll
      for (int r = 0; r < 4; ++r) red[0][wid][i * 16 + lhi * 4 + r] = mx[i][r];
  }
  __syncthreads();
#pragma unroll
  for (int i = 0; i < 2; ++i)
#pragma unroll
    for (int r = 0; r < 4; ++r) {
      int rl = i * 16 + lhi * 4 + r;
      float m_ = fmaxf(fmaxf(red[0][0][rl], red[0][1][rl]),
                       fmaxf(red[0][2][rl], red[0][3][rl]));
      float s_ = 0.f;
#pragma unroll
      for (int j = 0; j < 16; ++j) {
        float e = __expf(acc[i][j][r] - m_);
        acc[i][j][r] = e;
        s_ += e;
      }
#pragma unroll
      for (int off = 1; off < 16; off <<= 1) s_ += __shfl_xor(s_, off);
      sm[i][r] = s_;
    }
  if (lr == 0) {
#pragma unroll
    for (int i = 0; i < 2; ++i)
#pragma unroll
      for (int r = 0; r < 4; ++r) red[1][wid][i * 16 + lhi * 4 + r] = sm[i][r];
  }
  __syncthreads();

  float inv[2][4];
#pragma unroll
  for (int i = 0; i < 2; ++i)
#pragma unroll
    for (int r = 0; r < 4; ++r) {
      int rl = i * 16 + lhi * 4 + r;
      inv[i][r] = 1.0f / (red[1][0][rl] + red[1][1][rl] + red[1][2][rl] + red[1][3][rl]);
    }

  unsigned pb[2][16][2];
  {
    const size_t attn_base =
        (size_t)bh * 1024 * 1024 + ((size_t)q0) * 1024 + (size_t)(wid * 256);
#pragma unroll
    for (int i = 0; i < 2; ++i)
#pragma unroll
      for (int j = 0; j < 16; ++j) {
        float p0 = acc[i][j][0] * inv[i][0];
        float p1 = acc[i][j][1] * inv[i][1];
        float p2 = acc[i][j][2] * inv[i][2];
        float p3 = acc[i][j][3] * inv[i][3];
        size_t base = attn_base + (size_t)(i * 16 + lhi * 4) * 1024 + j * 16 + lr;
        attn_out[base] = p0;
        attn_out[base + 1024] = p1;
        attn_out[base + 2048] = p2;
        attn_out[base + 3072] = p3;
        pb[i][j][0] = (unsigned)f2bf(p0) | ((unsigned)f2bf(p1) << 16);
        pb[i][j][1] = (unsigned)f2bf(p2) | ((unsigned)f2bf(p3) << 16);
      }
  }

  char* sP = smem + wid * 4096;
  char* sV = smem + 16384 + wid * 8192;
  f32x4 oaccT[4][2] = {};

#pragma unroll
  for (int t = 0; t < 4; ++t) {
#pragma unroll
    for (int i = 0; i < 2; ++i)
#pragma unroll
      for (int jl = 0; jl < 4; ++jl) {
        int j = t * 4 + jl;
        int kvl2 = (jl * 16 + lr) * 2;
#pragma unroll
        for (int hp = 0; hp < 2; ++hp) {
          unsigned d = pb[i][j][hp];
          int qa = i * 16 + lhi * 4 + hp * 2;
          int qb = qa + 1;
          *(unsigned short*)(sP + qa * 128 + (kvl2 ^ ((qa & 7) << 4))) =
              (unsigned short)(d & 0xffff);
          *(unsigned short*)(sP + qb * 128 + (kvl2 ^ ((qb & 7) << 4))) =
              (unsigned short)(d >> 16);
        }
      }
    {
      int kvq = lane >> 2;
      int dq = (lane & 3) * 8;
#pragma unroll
      for (int rt = 0; rt < 2; ++rt)
#pragma unroll
        for (int dh = 0; dh < 2; ++dh) {
          int kvp2 = rt * 16 + kvq;
          int kvg = wid * 256 + t * 64 + kvp2 * 2;
          int d0 = dh * 32 + dq;
          bf16x8 v0 = *(const bf16x8*)&qkv[row0 + (size_t)kvg * 3072 + 2048 + hcol + d0];
          bf16x8 v1 = *(const bf16x8*)&qkv[row0 + (size_t)(kvg + 1) * 3072 + 2048 + hcol + d0];
#pragma unroll
          for (int e = 0; e < 8; ++e) {
            int d = d0 + e;
            unsigned dw = (unsigned)(unsigned short)v0[e] |
                          ((unsigned)(unsigned short)v1[e] << 16);
            *(unsigned*)(sV + d * 128 + ((kvp2 * 4) ^ ((d & 7) << 4))) = dw;
          }
        }
    }
#pragma unroll
    for (int c = 0; c < 2; ++c) {
      bf16x8 pf[2];
#pragma unroll
      for (int qt = 0; qt < 2; ++qt) {
        int q_ = qt * 16 + lr;
        pf[qt] = *(const bf16x8*)(sP + q_ * 128 + ((c * 64 + lhi * 16) ^ ((q_ & 7) << 4)));
      }
#pragma unroll
      for (int dt = 0; dt < 4; ++dt) {
        int d_ = dt * 16 + lr;
        bf16x8 vf = *(const bf16x8*)(sV + d_ * 128 + ((c * 64 + lhi * 16) ^ ((d_ & 7) << 4)));
        oaccT[dt][0] = MFMA16(vf, pf[0], oaccT[dt][0]);
        oaccT[dt][1] = MFMA16(vf, pf[1], oaccT[dt][1]);
      }
    }
  }

  __syncthreads();
  float* sAO = (float*)smem;
#pragma unroll
  for (int dt = 0; dt < 4; ++dt)
#pragma unroll
    for (int qt = 0; qt < 2; ++qt)
#pragma unroll
      for (int r = 0; r < 4; ++r) {
        int q_ = qt * 16 + lr;
        int d_ = dt * 16 + lhi * 4 + r;
        sAO[wid * 2080 + q_ * 65 + d_] = oaccT[dt][qt][r];
      }
  __syncthreads();
  {
    int q_ = tid >> 3;
    int d0 = (tid & 7) * 8;
    bf16x8 o;
#pragma unroll
    for (int e = 0; e < 8; ++e) {
      int d_ = d0 + e;
      float s = sAO[q_ * 65 + d_] + sAO[2080 + q_ * 65 + d_] +
                sAO[4160 + q_ * 65 + d_] + sAO[6240 + q_ * 65 + d_];
      o[e] = (short)f2bf(s);
    }
    *(bf16x8*)&ao[(size_t)(b * 1024 + q0 + q_) * 1024 + hcol + d0] = o;
  }
}

// ---------------- launch ----------------
extern "C" void kernel_launch(void* const* d_in, const int* in_sizes, int n_in,
                              void* d_out, int out_size, void* d_ws, size_t ws_size,
                              hipStream_t stream) {
  (void)in_sizes; (void)n_in; (void)out_size; (void)ws_size;
  const float* x     = (const float*)d_in[0];
  const float* ln1g  = (const float*)d_in[1];
  const float* ln1b  = (const float*)d_in[2];
  const float* qkvw  = (const float*)d_in[3];
  const float* projw = (const float*)d_in[4];
  const float* projb = (const float*)d_in[5];
  const float* g1    = (const float*)d_in[6];
  const float* ln2g  = (const float*)d_in[7];
  const float* ln2b  = (const float*)d_in[8];
  const float* fc1w  = (const float*)d_in[9];
  const float* fc1b  = (const float*)d_in[10];
  const float* fc2w  = (const float*)d_in[11];
  const float* fc2b  = (const float*)d_in[12];
  const float* g2    = (const float*)d_in[13];

  char* ws = (char*)d_ws;
  unsigned short* w_qkv  = (unsigned short*)(ws);              // 6 MB
  unsigned short* w_proj = (unsigned short*)(ws + 6291456);    // 2 MB
  unsigned short* w_fc1  = (unsigned short*)(ws + 8388608);    // 8 MB
  unsigned short* w_fc2  = (unsigned short*)(ws + 16777216);   // 8 MB
  unsigned short* n12    = (unsigned short*)(ws + 25165824);   // 8 MB (n1, later n2)
  unsigned short* qkvb   = (unsigned short*)(ws + 33554432);   // 24 MB (later h: 32 MB)
  unsigned short* hbuf   = qkvb;                               // h overlays qkv (dead)
  unsigned short* aob    = (unsigned short*)(ws + 58720256);   // 8 MB
  float*          x1     = (float*)(ws + 67108864);            // 16 MB

  float* outx = (float*)d_out;
  float* outattn = outx + (size_t)4096 * 1024;

  k_cvt4<<<12288, 256, 0, stream>>>(qkvw, projw, fc1w, fc2w,
                                    w_qkv, w_proj, w_fc1, w_fc2);

  k_ln<<<4096, 256, 0, stream>>>(x, ln1g, ln1b, n12);
  // qkv: M=4096 N=3072 K=1024 -> 12x16 = 192 blocks of 256^2
  k_gemm256<0><<<192, 512, 0, stream>>>(n12, w_qkv, 3072, 1024, 16,
                                        nullptr, qkvb);
  k_attn<<<dim3(32, 64), 256, 0, stream>>>(qkvb, outattn, aob);
  // proj: M=4096 N=1024 K=1024 -> 8x32 = 256 blocks of 128^2
  k_gemm_bt2<<<256, 256, 0, stream>>>(aob, w_proj, 1024, 1024, 32,
                                      projb, g1, x, x1);
  k_ln<<<4096, 256, 0, stream>>>(x1, ln2g, ln2b, n12);
  // fc1: M=4096 N=4096 K=1024 -> 16x16 = 256 blocks of 256^2
  k_gemm256<1><<<256, 512, 0, stream>>>(n12, w_fc1, 4096, 1024, 16,
                                        fc1b, hbuf);
  // fc2: M=4096 N=1024 K=4096 -> 8x32 = 256 blocks of 128^2
  k_gemm_bt2<<<256, 256, 0, stream>>>(hbuf, w_fc2, 1024, 4096, 32,
                                      fc2b, g2, x1, outx);
}